// Round 1
// baseline (1376.891 us; speedup 1.0000x reference)
//
#include <hip/hip_runtime.h>
#include <stdint.h>

// Problem constants (fixed by setup_inputs)
#define NN 4096
#define TT 256
#define SZ 8
#define KK 16

// ws layout (bytes):
//   Mb    : ushort[NN*NN]          @ 0           (32 MiB)  bf16 of exp(xi)*M
//   tempT : float [TT*NN]          @ 33554432    (4 MiB)   tempt transposed [t][n]
//   outs  : float [TT*NN]          @ 37748736    (4 MiB)   outs[t][n] = h_{t+1}[n]
//   h0    : float [NN]             @ 41943040    (16 KiB)
// total ~40 MiB

typedef unsigned short u16;

__device__ __forceinline__ u16 f2bf(float f) {
    uint32_t u = __float_as_uint(f);
    uint32_t r = (u + 0x7fffu + ((u >> 16) & 1u)) >> 16; // RNE
    return (u16)r;
}

// tempt[t][n] = sum_s x[n][t][s] * w[s]
__global__ void prep_tempt(const float* __restrict__ x, const float* __restrict__ w,
                           float* __restrict__ tempT) {
    int idx = blockIdx.x * blockDim.x + threadIdx.x;  // idx = t*NN + n  (coalesced write)
    int t = idx >> 12;
    int n = idx & (NN - 1);
    const float4* xp = (const float4*)(x + ((size_t)n * TT + t) * SZ);
    float4 a = xp[0], b = xp[1];
    float acc = a.x * w[0] + a.y * w[1] + a.z * w[2] + a.w * w[3]
              + b.x * w[4] + b.y * w[5] + b.z * w[6] + b.w * w[7];
    tempT[idx] = acc;
}

// Mb = bf16(exp(xi[0]) * M), 4 elements per thread
__global__ void conv_M(const float* __restrict__ M, const float* __restrict__ xi,
                       u16* __restrict__ Mb) {
    int idx = blockIdx.x * blockDim.x + threadIdx.x;   // 0 .. NN*NN/4
    float s = __expf(xi[0]);
    float4 v = ((const float4*)M)[idx];
    ushort4 o;
    o.x = f2bf(v.x * s);
    o.y = f2bf(v.y * s);
    o.z = f2bf(v.z * s);
    o.w = f2bf(v.w * s);
    ((ushort4*)Mb)[idx] = o;
}

__global__ void init_h(const float* __restrict__ hidden, float* __restrict__ h0) {
    int i = blockIdx.x * blockDim.x + threadIdx.x;
    if (i < NN) h0[i] = hidden[i];
}

// One recurrence step: hout[r] = dot(Mb[r,:], hin) + bcol[r]
// 512 threads = 8 waves, one wave per row, 8 rows/block, grid = NN/8 = 512 blocks.
__global__ __launch_bounds__(512) void step_kernel(const u16* __restrict__ Mb,
                                                   const float* __restrict__ bcol,
                                                   const float* __restrict__ hin,
                                                   float* __restrict__ hout) {
    __shared__ float hs[NN];
    int tid = threadIdx.x;
    // stage h into LDS: 4096 floats, 512 threads * 2 float4
    {
        const float4* hp = (const float4*)hin;
        float4* sp = (float4*)hs;
        sp[tid]       = hp[tid];
        sp[tid + 512] = hp[tid + 512];
    }
    __syncthreads();

    int w = tid >> 6, l = tid & 63;
    int r = blockIdx.x * 8 + w;
    const ushort4* Mr = (const ushort4*)(Mb + (size_t)r * NN);
    const float4*  h4 = (const float4*)hs;

    float acc = 0.f;
#pragma unroll
    for (int i = 0; i < 16; i++) {
        int idx = i * 64 + l;
        ushort4 m = Mr[idx];
        float4  h = h4[idx];
        acc += __uint_as_float((uint32_t)m.x << 16) * h.x
             + __uint_as_float((uint32_t)m.y << 16) * h.y
             + __uint_as_float((uint32_t)m.z << 16) * h.z
             + __uint_as_float((uint32_t)m.w << 16) * h.w;
    }
#pragma unroll
    for (int off = 32; off; off >>= 1) acc += __shfl_xor(acc, off, 64);
    if (l == 0) hout[r] = acc + bcol[r];
}

// d_out[0 .. 4096*240)   : output[n][tt] = outs[tt+16][n]
// d_out[4096*240 .. +4096): hidden_final = outs[255][:]
__global__ void emit(const float* __restrict__ outs, float* __restrict__ out) {
    int idx = blockIdx.x * blockDim.x + threadIdx.x;   // 0 .. 240*NN + NN
    if (idx < 240 * NN) {
        int tt = idx >> 12;          // idx = tt*NN + n (coalesced read)
        int n  = idx & (NN - 1);
        out[(size_t)n * 240 + tt] = outs[(size_t)(tt + KK) * NN + n];
    } else {
        int n = idx - 240 * NN;
        out[(size_t)240 * NN + n] = outs[(size_t)(TT - 1) * NN + n];
    }
}

extern "C" void kernel_launch(void* const* d_in, const int* in_sizes, int n_in,
                              void* d_out, int out_size, void* d_ws, size_t ws_size,
                              hipStream_t stream) {
    const float* x      = (const float*)d_in[0];
    const float* hidden = (const float*)d_in[1];
    const float* M      = (const float*)d_in[2];
    const float* w      = (const float*)d_in[3];
    const float* xi     = (const float*)d_in[4];
    // d_in[5] is k == 16, hard-coded as KK.

    char* ws = (char*)d_ws;
    u16*   Mb    = (u16*)ws;
    float* tempT = (float*)(ws + 33554432);
    float* outs  = (float*)(ws + 37748736);
    float* h0    = (float*)(ws + 41943040);
    float* out   = (float*)d_out;

    prep_tempt<<<(TT * NN) / 256, 256, 0, stream>>>(x, w, tempT);
    conv_M<<<(NN * NN / 4) / 256, 256, 0, stream>>>(M, xi, Mb);
    init_h<<<NN / 256, 256, 0, stream>>>(hidden, h0);

    for (int t = 0; t < TT; t++) {
        const float* hin = (t == 0) ? h0 : (outs + (size_t)(t - 1) * NN);
        step_kernel<<<NN / 8, 512, 0, stream>>>(Mb, tempT + (size_t)t * NN, hin,
                                                outs + (size_t)t * NN);
    }

    emit<<<(240 * NN + NN) / 256, 256, 0, stream>>>(outs, out);
}